// Round 8
// baseline (240.287 us; speedup 1.0000x reference)
//
#include <hip/hip_runtime.h>
#include <math.h>

// Problem constants: B=8, T=16, P=197, C=1024, R=8
#define BB 8
#define TT 16
#define PP 197
#define CC 1024
#define RR 8
#define NSEQ  (BB * PP)        // 1576 sequences = 1576 blocks
#define LORA_SCALE 2.0f        // alpha/rank = 16/8

__device__ __forceinline__ float sigf(float x) {
    x = fminf(fmaxf(x, -30.f), 30.f);
    return 1.0f / (1.0f + __expf(-x));
}
__device__ __forceinline__ float tanh_fast(float x) {
    x = fminf(fmaxf(x, -15.f), 15.f);
    float e = __expf(-2.0f * x);
    return (1.0f - e) / (1.0f + e);
}
__device__ __forceinline__ float dot4(const float4 a, const float4 b) {
    return a.x * b.x + a.y * b.y + a.z * b.z + a.w * b.w;
}

// ---------------------------------------------------------------------------
// k_fused4: R0's winning per-wave structure x2 waves per sequence.
// Session ranking: R0 fused/1-wave 75.8us < R6 fused/4-wave-LDS 84 < R1
// 3-split ~86 < R7 2-split ~95. Splits lose to the inter-kernel drain; R6
// lost to LDS-staged weights (residency cap + half the loads in flight).
// This keeps R0 verbatim per-wave (register-resident dw, 4-deep row
// pipeline, butterfly reduce) and fixes only R0's measured defect:
// occupancy (1576 waves -> 3152 waves, ~3.1/SIMD; VGPR~128 -> 4/SIMD cap
// -> whole grid co-resident; LDS 1KB).
//   Phase 1 (down): wave wv owns t = 8*wv..8*wv+7, 4-deep pipeline.
//   Phase 2 (LSTM): wave 0, lane = gate*8+rank, 3-shfl exchange
//                   (R6/R7-verified numerics, absmax 2.4e-4).
//   Phase 3 (up):   wave wv owns its 8 t's; per-g4 wA/wB hoisted; float4
//                   stores (1KB/instr vs R0's 256B dword stores).
// ---------------------------------------------------------------------------
__global__ __launch_bounds__(128, 2) void k_fused4(const float* __restrict__ hs,
                                                   const float* __restrict__ fm,
                                                   const float* __restrict__ dw,
                                                   const float* __restrict__ w_ih,
                                                   const float* __restrict__ w_hh,
                                                   const float* __restrict__ b_ih,
                                                   const float* __restrict__ b_hh,
                                                   const float* __restrict__ up,
                                                   float* __restrict__ out) {
    __shared__ float red_lds[TT][RR];   // masked down-projection
    __shared__ float h_lds[TT][RR];     // masked+scaled hidden states

    const int tid  = threadIdx.x;       // 128 threads = 2 waves
    const int lane = tid & 63;
    const int wv   = tid >> 6;          // 0..1
    const int seq  = blockIdx.x;
    const int b    = seq / PP;
    const int p    = seq - b * PP;
    const float* hsbase = hs + ((size_t)b * TT * PP + p) * CC;  // t-stride = PP*CC

    // ---- Phase 1: LoRA down. Wave wv: t = 8*wv .. 8*wv+7 (R0 structure) ----
    {
        float4 wreg[RR][4];             // dw register tile: lane owns cols k*256+lane*4
#pragma unroll
        for (int r = 0; r < RR; ++r)
#pragma unroll
            for (int k = 0; k < 4; ++k)
                wreg[r][k] = *(const float4*)(dw + r * CC + k * 256 + lane * 4);

        const int tbase = wv * 8;
        float4 buf[4][4];               // 4-row software pipeline (16 loads in flight)
#pragma unroll
        for (int t = 0; t < 4; ++t) {
            const float* rp = hsbase + (size_t)(tbase + t) * PP * CC;
#pragma unroll
            for (int k = 0; k < 4; ++k) buf[t][k] = *(const float4*)(rp + k * 256 + lane * 4);
        }
#pragma unroll
        for (int tt = 0; tt < 8; ++tt) {
            const int s = tt & 3;
            float acc[RR];
#pragma unroll
            for (int r = 0; r < RR; ++r) {
                float a = 0.f;
#pragma unroll
                for (int k = 0; k < 4; ++k) a += dot4(buf[s][k], wreg[r][k]);
                acc[r] = a;
            }
            if (tt + 4 < 8) {           // refill the slot just consumed
                const float* rp = hsbase + (size_t)(tbase + tt + 4) * PP * CC;
#pragma unroll
                for (int k = 0; k < 4; ++k) buf[s][k] = *(const float4*)(rp + k * 256 + lane * 4);
            }
#pragma unroll
            for (int d = 32; d >= 1; d >>= 1)
#pragma unroll
                for (int r = 0; r < RR; ++r) acc[r] += __shfl_xor(acc[r], d, 64);
            if (lane == 0) {
                const int t = tbase + tt;
                const float m = fm[b * TT + t];
                *(float4*)&red_lds[t][0] = make_float4(acc[0] * m, acc[1] * m,
                                                       acc[2] * m, acc[3] * m);
                *(float4*)&red_lds[t][4] = make_float4(acc[4] * m, acc[5] * m,
                                                       acc[6] * m, acc[7] * m);
            }
        }
    }
    __syncthreads();

    // ---- Phase 2: LSTM on wave 0; lane idx = gate*8 + rank (verified) ----
    if (wv == 0) {
        const int idx = lane & 31;          // lanes 32..63 mirror 0..31 (harmless)
        const int r   = idx & 7;
        const bool isG = (idx >> 3) == 2;   // gate order i,f,g,o; 'g' uses tanh
        float wr[8], whv[8];
        {
            const float* wip = w_ih + idx * 8;
            float4 a = *(const float4*)wip, b4 = *(const float4*)(wip + 4);
            wr[0] = a.x;  wr[1] = a.y;  wr[2] = a.z;  wr[3] = a.w;
            wr[4] = b4.x; wr[5] = b4.y; wr[6] = b4.z; wr[7] = b4.w;
            const float* whp = w_hh + idx * 8;
            float4 c4 = *(const float4*)whp, d4 = *(const float4*)(whp + 4);
            whv[0] = c4.x; whv[1] = c4.y; whv[2] = c4.z; whv[3] = c4.w;
            whv[4] = d4.x; whv[5] = d4.y; whv[6] = d4.z; whv[7] = d4.w;
        }
        const float bias = b_ih[idx] + b_hh[idx];

        float h = 0.f, c = 0.f;
#pragma unroll
        for (int t = 0; t < TT; ++t) {
            const float4 x0 = *(const float4*)&red_lds[t][0];   // broadcast read
            const float4 x1 = *(const float4*)&red_lds[t][4];
            const float xs[8] = {x0.x, x0.y, x0.z, x0.w, x1.x, x1.y, x1.z, x1.w};
            float gv = bias;
#pragma unroll
            for (int j = 0; j < 8; ++j) gv += wr[j] * xs[j];     // off-chain
#pragma unroll
            for (int j = 0; j < 8; ++j) gv += whv[j] * __shfl(h, j, 64);  // h chain
            const float sg = sigf(gv);
            const float tg = tanh_fast(gv);
            const float a  = isG ? tg : sg;                      // this lane's gate act
            const float fa = __shfl(a,  8 + r, 64);              // f-act of rank r
            const float ga = __shfl(a, 16 + r, 64);              // g-act
            const float oa = __shfl(a, 24 + r, 64);              // o-act
            c = fa * c + a * ga;          // valid on lanes idx<8 (a = i-act there)
            h = oa * tanh_fast(c);        // recurrent h is UNmasked (matches ref)
            if (lane < 8) h_lds[t][lane] = h * fm[b * TT + t] * LORA_SCALE;
        }
    }
    __syncthreads();

    // ---- Phase 3: LoRA up. Wave wv: t = 8*wv .. 8*wv+7; float4 stores ----
    {
        const int tbase = wv * 8;
        float* obase = out + ((size_t)b * TT * PP + p) * CC;
#pragma unroll
        for (int g4 = 0; g4 < 4; ++g4) {
            // up rows for the 4 consecutive output cols this lane owns
            const float* wp = up + (size_t)(g4 * 256 + lane * 4) * RR;
            float4 wA[4], wB[4];
#pragma unroll
            for (int c4 = 0; c4 < 4; ++c4) {
                wA[c4] = *(const float4*)(wp + c4 * RR);
                wB[c4] = *(const float4*)(wp + c4 * RR + 4);
            }
#pragma unroll
            for (int i = 0; i < 8; ++i) {
                const int t = tbase + i;
                const float4 h0 = *(const float4*)&h_lds[t][0];  // broadcast read
                const float4 h1 = *(const float4*)&h_lds[t][4];
                float4 o;
                o.x = dot4(h0, wA[0]) + dot4(h1, wB[0]);
                o.y = dot4(h0, wA[1]) + dot4(h1, wB[1]);
                o.z = dot4(h0, wA[2]) + dot4(h1, wB[2]);
                o.w = dot4(h0, wA[3]) + dot4(h1, wB[3]);
                *(float4*)(obase + (size_t)t * PP * CC + g4 * 256 + lane * 4) = o;
            }
        }
    }
}

extern "C" void kernel_launch(void* const* d_in, const int* in_sizes, int n_in,
                              void* d_out, int out_size, void* d_ws, size_t ws_size,
                              hipStream_t stream) {
    const float* hs  = (const float*)d_in[0];  // (B,T,P,C)
    const float* fm  = (const float*)d_in[2];  // (B,T)
    const float* dw  = (const float*)d_in[3];  // (R,C)
    const float* wih = (const float*)d_in[4];  // (4R,R)
    const float* whh = (const float*)d_in[5];  // (4R,R)
    const float* bih = (const float*)d_in[6];  // (4R,)
    const float* bhh = (const float*)d_in[7];  // (4R,)
    const float* up  = (const float*)d_in[8];  // (C,R)
    float* out = (float*)d_out;

    (void)d_ws; (void)ws_size;   // the 413MB poison fill is unconditional; ws unused

    // One 2-wave block per sequence: single launch, whole grid co-resident.
    k_fused4<<<NSEQ, 128, 0, stream>>>(hs, fm, dw, wih, whh, bih, bhh, up, out);
}